// Round 15
// baseline (134.792 us; speedup 1.0000x reference)
//
#include <hip/hip_runtime.h>
#include <hip/hip_bf16.h>
#include <hip/hip_fp16.h>

// GAT attention aggregator, fused. B=20000, N=32, D=128, H=256, O=128.
// R15 = R14 (f16 datapath + packed epilogue) with __fp16/_Float16 bit_cast
// shims around cvt_pkrtz/fdot2 (clang returns __fp16 vectors from the
// builtins; _Float16 vectors don't implicitly convert).

#define BB 20000
#define NN 32
#define DD 128
#define HH 256
#define OO 128
#define MB 4
#define ROWS 144         // 128 neib + 4 x (128..131) + 4 agg (132..135) + 8 junk
#define AG0 132

typedef _Float16 f16x8 __attribute__((ext_vector_type(8)));
typedef _Float16 f16x4 __attribute__((ext_vector_type(4)));
typedef _Float16 h2    __attribute__((ext_vector_type(2)));
typedef __fp16   g2    __attribute__((ext_vector_type(2)));   // builtin-native
typedef float f32x4 __attribute__((ext_vector_type(4)));

__device__ __forceinline__ h2 pkrtz(float a, float b) {
    return __builtin_bit_cast(h2, __builtin_amdgcn_cvt_pkrtz(a, b));
}
__device__ __forceinline__ float dot2acc(h2 x, h2 c, float ep) {
#if __has_builtin(__builtin_amdgcn_fdot2)
    return __builtin_amdgcn_fdot2(__builtin_bit_cast(g2, x),
                                  __builtin_bit_cast(g2, c), ep, false);
#else
    return ep + (float)x[0] * (float)c[0] + (float)x[1] * (float)c[1];
#endif
}

__global__ void prep_weights(const float* __restrict__ Watt,
                             const float* __restrict__ Wfcx,
                             const float* __restrict__ Wfcn,
                             _Float16* __restrict__ WaT,
                             _Float16* __restrict__ WcT) {
    int idx = blockIdx.x * 256 + threadIdx.x;   // 0..65535
    int half = idx >> 15;
    int j = idx & 32767;
    int c = j >> 7, k = j & 127;
    if (half == 0) {
        WaT[j] = (_Float16)Watt[k * HH + c];     // WaT[h][k] = W_att[k][h]
    } else {
        float wv = (c < OO) ? Wfcx[k * OO + c] : Wfcn[k * OO + (c - OO)];
        WcT[j] = (_Float16)wv;                   // WcT[c][k]
    }
}

__launch_bounds__(256, 4)
__global__ void gat_fused(const float* __restrict__ x,
                          const float* __restrict__ neibs,
                          const float* __restrict__ a,
                          const _Float16* __restrict__ WaT,
                          const _Float16* __restrict__ WcT,
                          float* __restrict__ out) {
    __shared__ _Float16 rowsS[ROWS * 128];       // 36,864 B, XOR-swizzled rows
    __shared__ float e_part[4][ROWS];            //  2,304 B
    __shared__ float att_s[MB][NN];              //    512 B

    // ---- round-1 desync (kept from R13; harmless) ----
    {
        const unsigned bid = blockIdx.x;
        if (bid < 1280) {
            const unsigned k = (bid * 2654435761u) >> 30;
            for (unsigned i = 0; i < k; ++i)
                __builtin_amdgcn_s_sleep(40);
        }
    }

    const int tid = threadIdx.x;
    const int w   = tid >> 6;      // wave 0..3
    const int l   = tid & 63;
    const int lr  = l & 15;
    const int lg  = l >> 4;
    const int b0  = blockIdx.x * MB;
    char* rbase = (char*)rowsS;

    // staging: row = it*8 + (tid>>5); byte off (row*256 + 2k) ^ ((row&7)<<4)
    const int stbase = (tid >> 5) * 256 + ((8 * (tid & 31)) ^ ((tid >> 5) << 4));
    int abase[4];
#pragma unroll
    for (int ks = 0; ks < 4; ++ks)
        abase[ks] = lr * 256 + ((ks * 64 + lg * 16) ^ ((lr & 7) << 4));

    // ---- stage 128 neib rows + 4 x rows into swizzled LDS as f16 ----
    {
        const float4* np4 = (const float4*)(neibs + (size_t)b0 * NN * DD);
#pragma unroll
        for (int it = 0; it < 16; ++it) {
            float4 v = np4[it * 256 + tid];
            h2 s0 = pkrtz(v.x, v.y), s1 = pkrtz(v.z, v.w);
            uint2 s = { __builtin_bit_cast(unsigned, s0), __builtin_bit_cast(unsigned, s1) };
            *(uint2*)(rbase + stbase + it * 2048) = s;
        }
        if (tid < 128) {   // x rows 128..131
            float4 v = ((const float4*)(x + (size_t)b0 * DD))[tid];
            h2 s0 = pkrtz(v.x, v.y), s1 = pkrtz(v.z, v.w);
            uint2 s = { __builtin_bit_cast(unsigned, s0), __builtin_bit_cast(unsigned, s1) };
            *(uint2*)(rbase + stbase + 32768) = s;
        }
    }

    // ---- W_att panel (A-operand) + packed a-coef pairs ----
    f16x8 bw[4][4];
    h2 c2N[4][2], c2X[4][2];
#pragma unroll
    for (int c4 = 0; c4 < 4; ++c4) {
        int col = (w * 4 + c4) * 16 + lr;
#pragma unroll
        for (int ks = 0; ks < 4; ++ks)
            bw[c4][ks] = *(const f16x8*)(WaT + col * 128 + ks * 32 + lg * 8);
        int hb = (w * 4 + c4) * 16 + 4 * lg;
        c2N[c4][0] = pkrtz(a[HH + hb + 0], a[HH + hb + 1]);
        c2N[c4][1] = pkrtz(a[HH + hb + 2], a[HH + hb + 3]);
        c2X[c4][0] = pkrtz(a[hb + 0], a[hb + 1]);
        c2X[c4][1] = pkrtz(a[hb + 2], a[hb + 3]);
    }
    const h2 k001 = { (_Float16)0.01f, (_Float16)0.01f };

    __syncthreads();                              // B1: staged rows visible

    // ---- score (swapped): acc = W^T-tile x R-rows = S^T[h, r] ----
    // Per lane all 16 acc elems belong to ONE row r=lr; h = c4*16 + 4*lg + i.
#pragma unroll
    for (int rt = 0; rt < 9; ++rt) {
        const int off = (rt < 8) ? rt * 4096 : 32768;
        f16x8 af[4];
#pragma unroll
        for (int ks = 0; ks < 4; ++ks)
            af[ks] = *(const f16x8*)(rbase + abase[ks] + off);
        f32x4 acc[4];
#pragma unroll
        for (int c4 = 0; c4 < 4; ++c4) acc[c4] = (f32x4){0.f, 0.f, 0.f, 0.f};
#pragma unroll
        for (int ks = 0; ks < 4; ++ks)
#pragma unroll
            for (int c4 = 0; c4 < 4; ++c4)
                acc[c4] = __builtin_amdgcn_mfma_f32_16x16x32_f16(bw[c4][ks], af[ks], acc[c4], 0, 0, 0);
        float ep = 0.f;
#pragma unroll
        for (int c4 = 0; c4 < 4; ++c4) {
            h2 s01 = pkrtz(acc[c4][0], acc[c4][1]);
            h2 s23 = pkrtz(acc[c4][2], acc[c4][3]);
            h2 l01 = __builtin_elementwise_max(s01, s01 * k001);
            h2 l23 = __builtin_elementwise_max(s23, s23 * k001);
            h2 ca = (rt == 8) ? c2X[c4][0] : c2N[c4][0];
            h2 cb = (rt == 8) ? c2X[c4][1] : c2N[c4][1];
            ep = dot2acc(l01, ca, ep);
            ep = dot2acc(l23, cb, ep);
        }
        ep += __shfl_xor(ep, 16);
        ep += __shfl_xor(ep, 32);
        if (l < 16) e_part[w][((rt < 8) ? rt * 16 : 128) + l] = ep;
    }
    __syncthreads();                              // B2: e_part complete

    // ---- combine e, lrelu(0.2), softmax over 32 neighbors (threads 0..127) ----
    if (tid < 128) {
        const int bloc = tid >> 5;
        const int nloc = tid & 31;
        float sn = e_part[0][tid] + e_part[1][tid] + e_part[2][tid] + e_part[3][tid];
        float sx = e_part[0][128 + bloc] + e_part[1][128 + bloc] +
                   e_part[2][128 + bloc] + e_part[3][128 + bloc];
        float e = sx + sn;
        e = (e > 0.f) ? e : 0.2f * e;
        float mx = e;
#pragma unroll
        for (int m = 16; m >= 1; m >>= 1) mx = fmaxf(mx, __shfl_xor(mx, m, 32));
        float ex = __expf(e - mx);
        float sum = ex;
#pragma unroll
        for (int m = 16; m >= 1; m >>= 1) sum += __shfl_xor(sum, m, 32);
        att_s[bloc][nloc] = ex / sum;
    }
    __syncthreads();                              // B3: att_s ready

    // ---- WcT panel loads issue here; latency hides under aggregation ----
    f16x8 bff[4][4];
#pragma unroll
    for (int c4 = 0; c4 < 4; ++c4)
#pragma unroll
        for (int ks = 0; ks < 4; ++ks)
            bff[c4][ks] = *(const f16x8*)(WcT + ((w * 4 + c4) * 16 + lr) * 128 + ks * 32 + lg * 8);

    // ---- aggregation: wave w = node w; half-waves take even/odd neighbors ----
    {
        const int half = l >> 5, li = l & 31;
        const int agbase = w * 8192 + 256 * half + ((8 * li) ^ (half << 4));
        float ag[4] = {0.f, 0.f, 0.f, 0.f};
#pragma unroll
        for (int i = 0; i < 16; ++i) {
            float wv = att_s[w][2 * i + half];
            f16x4 v = *(const f16x4*)(rbase + (agbase ^ ((2 * i & 7) << 4)) + 512 * i);
#pragma unroll
            for (int j = 0; j < 4; ++j) ag[j] = fmaf(wv, (float)v[j], ag[j]);
        }
#pragma unroll
        for (int j = 0; j < 4; ++j) ag[j] += __shfl_xor(ag[j], 32);
        if (half == 0) {
            int row = AG0 + w;                    // row&7 = 4+w
            int off = row * 256 + ((8 * li) ^ ((row & 7) << 4));
            f16x4 s = { (_Float16)ag[0], (_Float16)ag[1], (_Float16)ag[2], (_Float16)ag[3] };
            *(f16x4*)(rbase + off) = s;
        }
    }
    __syncthreads();                              // B4: agg rows visible

    // ---- final matmul: [x;agg;junk](16x128) @ WcT^T(128x256), masked store ----
    {
        f16x8 af[4];
#pragma unroll
        for (int ks = 0; ks < 4; ++ks)
            af[ks] = *(const f16x8*)(rbase + abase[ks] + 32768);  // rows 128+lr
        f32x4 acc[4];
#pragma unroll
        for (int c4 = 0; c4 < 4; ++c4) acc[c4] = (f32x4){0.f, 0.f, 0.f, 0.f};
#pragma unroll
        for (int ks = 0; ks < 4; ++ks)
#pragma unroll
            for (int c4 = 0; c4 < 4; ++c4)
                acc[c4] = __builtin_amdgcn_mfma_f32_16x16x32_f16(af[ks], bff[c4][ks], acc[c4], 0, 0, 0);
#pragma unroll
        for (int c4 = 0; c4 < 4; ++c4) {
            int col = (w * 4 + c4) * 16 + lr;
#pragma unroll
            for (int reg = 0; reg < 4; ++reg) {
                int i = lg * 4 + reg;             // C row: 0..3 = x, 4..7 = agg
                bool doit = (col < 128) ? (i < 4) : (i >= 4 && i < 8);
                if (doit) {
                    float v = fmaxf(acc[c4][reg], 0.f);
                    out[(size_t)(b0 + (i & 3)) * 256 + col] = v;
                }
            }
        }
    }
}

extern "C" void kernel_launch(void* const* d_in, const int* in_sizes, int n_in,
                              void* d_out, int out_size, void* d_ws, size_t ws_size,
                              hipStream_t stream) {
    const float* x    = (const float*)d_in[0];
    const float* nb   = (const float*)d_in[1];
    const float* Watt = (const float*)d_in[2];
    const float* Wfcx = (const float*)d_in[3];
    const float* Wfcn = (const float*)d_in[4];
    const float* a    = (const float*)d_in[5];
    _Float16* WaT = (_Float16*)d_ws;
    _Float16* WcT = WaT + 32768;
    float* o = (float*)d_out;

    prep_weights<<<256, 256, 0, stream>>>(Watt, Wfcx, Wfcn, WaT, WcT);
    gat_fused<<<BB / MB, 256, 0, stream>>>(x, nb, a, WaT, WcT, o);
}